// Round 11
// baseline (364.397 us; speedup 1.0000x reference)
//
#include <hip/hip_runtime.h>

#define T_STEPS 256
#define BATCH   512
#define DIN     256
#define HDIM    256

typedef unsigned int u32;
typedef _Float16 h2 __attribute__((ext_vector_type(2)));

__device__ __forceinline__ u32 pack2(float a, float b) {
    return __builtin_bit_cast(u32, __builtin_amdgcn_cvt_pkrtz(a, b));
}
__device__ __forceinline__ float dot2(u32 a, u32 b, float acc) {
    return __builtin_amdgcn_fdot2(__builtin_bit_cast(h2, a),
                                  __builtin_bit_cast(h2, b), acc, false);
}
__device__ __forceinline__ float rcpf(float x) { return __builtin_amdgcn_rcpf(x); }
__device__ __forceinline__ float fast_sigmoid(float x) {
    return rcpf(1.0f + __expf(-x));
}
__device__ __forceinline__ float fast_tanh(float x) {
    return 1.0f - 2.0f * rcpf(__expf(2.0f * x) + 1.0f);
}

// DPP lane permute (VALU, not DS pipe). Invalid lanes keep own value.
template<int CTRL>
__device__ __forceinline__ float dppf(float x) {
    int xi = __builtin_bit_cast(int, x);
    return __builtin_bit_cast(float,
        __builtin_amdgcn_update_dpp(xi, xi, CTRL, 0xF, 0xF, false));
}
#define DPP_XOR1  0xB1   // quad_perm [1,0,3,2]
#define DPP_XOR2  0x4E   // quad_perm [2,3,0,1]
#define DPP_HMIR  0x141  // row_half_mirror (xor4 on quad-uniform data)
#define DPP_SHR1  0x111  // lane i <- i-1
#define DPP_SHR2  0x112
#define DPP_SHR4  0x114
#define DPP_SHL1  0x101  // lane i <- i+1

// LDS-only barrier: don't drain vmcnt (global loads/stores stay in flight)
__device__ __forceinline__ void lds_barrier() {
    asm volatile("s_waitcnt lgkmcnt(0)\n\ts_barrier" ::: "memory");
}

// ---------------------------------------------------------------------------
// Fused QLSTM, 8 waves (512 threads) per batch element -> 16 waves/CU
// (4/SIMD). Phase A: wave w owns dims [64w,64w+64) of [x;h]. Phase B split:
// p=0 (waves 0-3, thread=h-dim) computes f,i; p=1 computes g,o -> giS.
// Phases D/E redundant per wave. 3 lgkm-only barriers/step (A, B2, C).
// hS/xS staging is intra-wave (writer wave == reader wave) -> no barrier E.
// ---------------------------------------------------------------------------
__launch_bounds__(512, 4)
__global__ void qlstm_fused(const float* __restrict__ inputs,
                            const float* __restrict__ W_proj,
                            const float* __restrict__ b_proj,
                            const float* __restrict__ theta_gate,
                            const float* __restrict__ W_qproj,
                            const float* __restrict__ b_qproj,
                            const float* __restrict__ theta_attn,
                            const float* __restrict__ W_attn_proj,
                            const float* __restrict__ b_attn_proj,
                            const float* __restrict__ W_attn_back,
                            const float* __restrict__ b_attn_back,
                            float* __restrict__ out) {
    const int tid = threadIdx.x;
    const int b   = blockIdx.x;
    const int w   = tid >> 6;       // wave 0..7
    const int lw  = tid & 63;       // lane in wave
    const int g   = lw & 31;        // gate 0..31 (phase A)
    const int q   = lw & 7;         // hm chunk (D)
    const int o   = lw >> 3;        // attn output (D)
    const int p   = tid >> 8;       // half-block: 0 = waves 0-3, 1 = waves 4-7
    const int h   = tid & 255;      // h-dim (phases B/E)

    __shared__ __align__(16) u32 hS[128];     // h    f16[256]
    __shared__ __align__(16) u32 xS[256];     // x_t  f16[256] x 2 buffers
    __shared__ __align__(16) u32 hmS[160];    // hmid f16[256], stride-20 chunks
    __shared__ __align__(16) u32 ogS[128];    // 8 waves x 16 u32
    __shared__ __align__(16) float caS[64];   // 8 waves x 8 attn cosines
    __shared__ __align__(16) float preS[256]; // 8 waves x 32 gate partials
    __shared__ __align__(16) u32 giS[256];    // pack2(gv, ov) per h-dim

    // ---- register-resident weights ----
    // Phase A: wave w covers dims [64w, 64w+64) of the 512-dim [x;h];
    // lane-half (lw>>5) covers 32 of those dims.
    u32 WP[16];
    {
        const int dbase = 64 * w + (lw >> 5) * 32;
        #pragma unroll
        for (int i = 0; i < 16; ++i)
            WP[i] = pack2(W_proj[(dbase + 2 * i) * 32 + g],
                          W_proj[(dbase + 2 * i + 1) * 32 + g]);
    }
    u32 WqpP[4];                    // W_qproj column h (shared by all types)
    #pragma unroll
    for (int k = 0; k < 4; ++k)
        WqpP[k] = pack2(W_qproj[(2 * k) * HDIM + h],
                        W_qproj[(2 * k + 1) * HDIM + h]);
    u32 WapP[16];                   // W_attn_proj dims 32q.., output o
    #pragma unroll
    for (int i = 0; i < 16; ++i)
        WapP[i] = pack2(W_attn_proj[(32 * q + 2 * i) * 8 + o],
                        W_attn_proj[(32 * q + 2 * i + 1) * 8 + o]);
    u32 WabP[4];                    // W_attn_back column h
    #pragma unroll
    for (int k = 0; k < 4; ++k)
        WabP[k] = pack2(W_attn_back[(2 * k) * HDIM + h],
                        W_attn_back[(2 * k + 1) * HDIM + h]);
    const float bqp  = b_qproj[h];
    const float bap  = b_attn_proj[o] + theta_attn[o];
    const float bab  = b_attn_back[h];
    const float bias = b_proj[g] + theta_gate[g & 7];

    // ---- init: h = 0, stage x_0 into buffer 0 ----
    if (tid < 128) hS[tid] = 0u;
    if (tid < 256) {
        float x0  = inputs[(size_t)b * DIN + tid];
        float x0n = dppf<DPP_SHL1>(x0);
        if (!(tid & 1)) xS[tid >> 1] = pack2(x0, x0n);
    }
    float cx = 0.f, hx = 0.f;
    __syncthreads();

    for (int t = 0; t < T_STEPS; ++t) {
        const int xb = (t & 1) << 7;
        float xn = 0.f;
        if (p == 0 && t + 1 < T_STEPS)
            xn = inputs[((size_t)(t + 1) * BATCH + b) * DIN + tid];

        // ---- Phase A: wave w dots its 64-dim slice of [x;h] ----
        const u32* srcp = (w < 4) ? &xS[xb + 32 * w + (lw >> 5) * 16]
                                  : &hS[32 * (w - 4) + (lw >> 5) * 16];
        uint4 v0 = ((const uint4*)srcp)[0];
        uint4 v1 = ((const uint4*)srcp)[1];
        uint4 v2 = ((const uint4*)srcp)[2];
        uint4 v3 = ((const uint4*)srcp)[3];
        float a0 = dot2(v0.x, WP[ 0], 0.f);
        a0 = dot2(v0.y, WP[ 1], a0);
        a0 = dot2(v0.z, WP[ 2], a0);
        a0 = dot2(v0.w, WP[ 3], a0);
        float a1 = dot2(v1.x, WP[ 4], 0.f);
        a1 = dot2(v1.y, WP[ 5], a1);
        a1 = dot2(v1.z, WP[ 6], a1);
        a1 = dot2(v1.w, WP[ 7], a1);
        float a2 = dot2(v2.x, WP[ 8], 0.f);
        a2 = dot2(v2.y, WP[ 9], a2);
        a2 = dot2(v2.z, WP[10], a2);
        a2 = dot2(v2.w, WP[11], a2);
        float a3 = dot2(v3.x, WP[12], 0.f);
        a3 = dot2(v3.y, WP[13], a3);
        a3 = dot2(v3.z, WP[14], a3);
        a3 = dot2(v3.w, WP[15], a3);
        float part = (a0 + a1) + (a2 + a3);
        part += __shfl_xor(part, 32);
        if (lw < 32) preS[w * 32 + lw] = part;
        lds_barrier();                          // barrier A
        float pre = (((preS[g      ] + preS[ 32 + g]) +
                      (preS[ 64 + g] + preS[ 96 + g])) +
                     ((preS[128 + g] + preS[160 + g]) +
                      (preS[192 + g] + preS[224 + g]))) + bias;
        float cq = __cosf(pre);

        // prefix/butterfly over the 8 qubits — all DPP
        float s = cq;
        { float u1 = dppf<DPP_SHR1>(s); if ((g & 7) >= 1) s *= u1; }
        { float u2 = dppf<DPP_SHR2>(s); if ((g & 7) >= 2) s *= u2; }
        { float u4 = dppf<DPP_SHR4>(s); if ((g & 7) >= 4) s *= u4; }
        float v = ((g & 7) == 0) ? 1.0f : cq;
        v *= dppf<DPP_XOR1>(v);
        v *= dppf<DPP_XOR2>(v);
        v *= dppf<DPP_HMIR>(v);
        float outv = ((g & 7) == 0) ? v : s;
        float onx  = dppf<DPP_SHL1>(outv);
        if (lw < 32 && !(lw & 1))
            ogS[w * 16 + (lw >> 1)] = pack2(outv, onx);
        // intra-wave LDS RAW -> compiler lgkmcnt wait, no barrier

        // ---- Phase B: half-block p computes gate types {2p, 2p+1} ----
        const uint4* ogp = (const uint4*)&ogS[w * 16];
        uint4 ogA = ogp[2 * p];
        uint4 ogB = ogp[2 * p + 1];
        float dA = dot2(ogA.x, WqpP[0], bqp);
        dA = dot2(ogA.y, WqpP[1], dA);
        dA = dot2(ogA.z, WqpP[2], dA);
        dA = dot2(ogA.w, WqpP[3], dA);
        float dB = dot2(ogB.x, WqpP[0], bqp);
        dB = dot2(ogB.y, WqpP[1], dB);
        dB = dot2(ogB.z, WqpP[2], dB);
        dB = dot2(ogB.w, WqpP[3], dB);
        float fv = 0.f, iv = 0.f;
        if (p == 0) {
            fv = fast_sigmoid(dA);              // forget
            iv = fast_sigmoid(dB);              // input
        } else {
            float gv = fast_tanh(dA);           // cell candidate
            float ov = fast_sigmoid(dB);        // output
            giS[h] = pack2(gv, ov);
        }
        lds_barrier();                          // barrier B2
        if (p == 0) {
            h2 gi = __builtin_bit_cast(h2, giS[h]);
            cx = fmaf(fv, cx, iv * (float)gi[0]);
            float hm = (float)gi[1] * fast_tanh(cx);
            float hmn = dppf<DPP_SHL1>(hm);
            if (!(tid & 1))
                hmS[(tid >> 5) * 20 + ((tid >> 1) & 15)] = pack2(hm, hmn);
        }
        lds_barrier();                          // barrier C

        // ---- Phase D: attn projection (redundant per wave) ----
        const uint4* mp = (const uint4*)&hmS[q * 20];
        uint4 m0 = mp[0], m1 = mp[1], m2 = mp[2], m3 = mp[3];
        float s0 = dot2(m0.x, WapP[ 0], 0.f);
        s0 = dot2(m0.y, WapP[ 1], s0);
        s0 = dot2(m0.z, WapP[ 2], s0);
        s0 = dot2(m0.w, WapP[ 3], s0);
        float s1 = dot2(m1.x, WapP[ 4], 0.f);
        s1 = dot2(m1.y, WapP[ 5], s1);
        s1 = dot2(m1.z, WapP[ 6], s1);
        s1 = dot2(m1.w, WapP[ 7], s1);
        float s2 = dot2(m2.x, WapP[ 8], 0.f);
        s2 = dot2(m2.y, WapP[ 9], s2);
        s2 = dot2(m2.z, WapP[10], s2);
        s2 = dot2(m2.w, WapP[11], s2);
        float s3 = dot2(m3.x, WapP[12], 0.f);
        s3 = dot2(m3.y, WapP[13], s3);
        s3 = dot2(m3.z, WapP[14], s3);
        s3 = dot2(m3.w, WapP[15], s3);
        float sd = (s0 + s1) + (s2 + s3);
        sd += dppf<DPP_XOR1>(sd);
        sd += dppf<DPP_XOR2>(sd);
        sd += dppf<DPP_HMIR>(sd);
        float co = __cosf(sd + bap);
        if (!(lw & 7)) caS[w * 8 + o] = co;     // per-wave copy, same-wave read

        // ---- Phase E: hx = attn-qgate . W_attn_back + b (redundant) ----
        float4 cA = *(const float4*)&caS[w * 8];
        float4 cB = *(const float4*)&caS[w * 8 + 4];
        float p1 = cA.x * cA.y;
        float p2 = p1 * cA.z;
        float p3 = p2 * cA.w;
        float p4 = p3 * cB.x;
        float p5 = p4 * cB.y;
        float p6 = p5 * cB.z;
        float p7 = p6 * cB.w;
        float q12 = cA.y * cA.z, q34 = cA.w * cB.x, q56 = cB.y * cB.z;
        float p0 = (q12 * q34) * (q56 * cB.w);
        u32 oq0 = pack2(p0, p1);
        u32 oq1 = pack2(p2, p3);
        u32 oq2 = pack2(p4, p5);
        u32 oq3 = pack2(p6, p7);
        float hv = dot2(oq0, WabP[0], bab);
        hv = dot2(oq1, WabP[1], hv);
        hv = dot2(oq2, WabP[2], hv);
        hv = dot2(oq3, WabP[3], hv);
        hx = hv;
        // p=1: output store + hS staging (writer wave == reader wave in A)
        if (p == 1)
            out[((size_t)t * BATCH + b) * HDIM + h] = hx;
        float hxn = dppf<DPP_SHL1>(hx);
        if (p == 1 && !(tid & 1))
            hS[h >> 1] = pack2(hx, hxn);
        // p=0: stage prefetched x_{t+1} (writer wave == reader wave in A)
        if (p == 0) {
            float xnx = dppf<DPP_SHL1>(xn);
            if (!(tid & 1)) xS[(xb ^ 128) + (tid >> 1)] = pack2(xn, xnx);
        }
        // no barrier E (hS/xS intra-wave; preS WAR covered by B2/C,
        // hmS WAR covered by next step's A+B2, giS WAR by C + next A)
    }

    const size_t base = (size_t)T_STEPS * BATCH * HDIM;
    if (p == 0) {
        out[base + (size_t)b * HDIM + tid] = hx;
        out[base + (size_t)BATCH * HDIM + (size_t)b * HDIM + tid] = cx;
    }
}

extern "C" void kernel_launch(void* const* d_in, const int* in_sizes, int n_in,
                              void* d_out, int out_size, void* d_ws, size_t ws_size,
                              hipStream_t stream) {
    const float* inputs      = (const float*)d_in[0];
    const float* W_proj      = (const float*)d_in[1];
    const float* b_proj      = (const float*)d_in[2];
    const float* theta_gate  = (const float*)d_in[3];
    const float* W_qproj     = (const float*)d_in[4];
    const float* b_qproj     = (const float*)d_in[5];
    const float* theta_attn  = (const float*)d_in[6];
    const float* W_attn_proj = (const float*)d_in[7];
    const float* b_attn_proj = (const float*)d_in[8];
    const float* W_attn_back = (const float*)d_in[9];
    const float* b_attn_back = (const float*)d_in[10];
    float* outp = (float*)d_out;

    qlstm_fused<<<BATCH, 512, 0, stream>>>(
        inputs, W_proj, b_proj, theta_gate, W_qproj, b_qproj, theta_attn,
        W_attn_proj, b_attn_proj, W_attn_back, b_attn_back, outp);
}

// Round 12
// 296.498 us; speedup vs baseline: 1.2290x; 1.2290x over previous
//
#include <hip/hip_runtime.h>

#define T_STEPS 256
#define BATCH   512
#define DIN     256
#define HDIM    256

typedef unsigned int u32;
typedef _Float16 h2 __attribute__((ext_vector_type(2)));

__device__ __forceinline__ u32 pack2(float a, float b) {
    return __builtin_bit_cast(u32, __builtin_amdgcn_cvt_pkrtz(a, b));
}
__device__ __forceinline__ float dot2(u32 a, u32 b, float acc) {
    return __builtin_amdgcn_fdot2(__builtin_bit_cast(h2, a),
                                  __builtin_bit_cast(h2, b), acc, false);
}
__device__ __forceinline__ u32 rl(u32 v, int lane) {
    return (u32)__builtin_amdgcn_readlane((int)v, lane);
}
__device__ __forceinline__ float rlf(float v, int lane) {
    return __builtin_bit_cast(float,
        __builtin_amdgcn_readlane(__builtin_bit_cast(int, v), lane));
}
__device__ __forceinline__ float rcpf(float x) { return __builtin_amdgcn_rcpf(x); }
__device__ __forceinline__ float fast_sigmoid(float x) {
    return rcpf(1.0f + __expf(-x));
}
__device__ __forceinline__ float fast_tanh(float x) {
    return 1.0f - 2.0f * rcpf(__expf(2.0f * x) + 1.0f);
}

// DPP lane permute (VALU, not DS pipe). Invalid lanes keep own value.
template<int CTRL>
__device__ __forceinline__ float dppf(float x) {
    int xi = __builtin_bit_cast(int, x);
    return __builtin_bit_cast(float,
        __builtin_amdgcn_update_dpp(xi, xi, CTRL, 0xF, 0xF, false));
}
#define DPP_XOR1  0xB1   // quad_perm [1,0,3,2]
#define DPP_XOR2  0x4E   // quad_perm [2,3,0,1]
#define DPP_HMIR  0x141  // row_half_mirror (xor4 on quad-uniform data)
#define DPP_SHR1  0x111  // lane i <- i-1
#define DPP_SHR2  0x112
#define DPP_SHR4  0x114
#define DPP_SHL1  0x101  // lane i <- i+1

// LDS-only barrier: don't drain vmcnt (global loads/stores stay in flight)
__device__ __forceinline__ void lds_barrier() {
    asm volatile("s_waitcnt lgkmcnt(0)\n\ts_barrier" ::: "memory");
}

// ---------------------------------------------------------------------------
// Fused QLSTM (r10 structure + register-broadcast og/ca via readlane).
// 4 waves/batch-element, TWO lgkm-only barriers per step:
//   bar A: preS RAW (cross-wave gate reduce)  [also hmS WAR]
//   bar C: hmS RAW (cell -> attn projection)  [also preS WAR]
// hS/xS flows are intra-wave; og and attn-cosine broadcasts are pure-register
// (v_readlane from known lanes) -> no ogS/caS LDS and no lgkm waits there.
// ---------------------------------------------------------------------------
__launch_bounds__(256, 2)
__global__ void qlstm_fused(const float* __restrict__ inputs,
                            const float* __restrict__ W_proj,
                            const float* __restrict__ b_proj,
                            const float* __restrict__ theta_gate,
                            const float* __restrict__ W_qproj,
                            const float* __restrict__ b_qproj,
                            const float* __restrict__ theta_attn,
                            const float* __restrict__ W_attn_proj,
                            const float* __restrict__ b_attn_proj,
                            const float* __restrict__ W_attn_back,
                            const float* __restrict__ b_attn_back,
                            float* __restrict__ out) {
    const int tid  = threadIdx.x;
    const int b    = blockIdx.x;
    const int w    = tid >> 6;      // wave 0..3
    const int lw   = tid & 63;      // lane in wave
    const int g    = lw & 31;       // gate 0..31 (phase A)
    const int q    = lw & 7;        // hm chunk (D)
    const int o    = lw >> 3;       // attn output (D)

    __shared__ __align__(16) u32 hS[128];     // h    f16[256] packed
    __shared__ __align__(16) u32 xS[256];     // x_t  f16[256] x 2 buffers
    __shared__ __align__(16) u32 hmS[160];    // hmid f16[256], stride-20 chunks
    __shared__ __align__(16) float preS[256]; // 4 waves x 64 half-partials

    // ---- register-resident weights ----
    u32 WxP[16], WhP[16];
    {
        const int dbase = 64 * w + (lw >> 5) * 32;
        #pragma unroll
        for (int i = 0; i < 16; ++i) {
            WxP[i] = pack2(W_proj[(dbase + 2 * i) * 32 + g],
                           W_proj[(dbase + 2 * i + 1) * 32 + g]);
            WhP[i] = pack2(W_proj[(DIN + dbase + 2 * i) * 32 + g],
                           W_proj[(DIN + dbase + 2 * i + 1) * 32 + g]);
        }
    }
    u32 WqpP[4];
    #pragma unroll
    for (int p = 0; p < 4; ++p)
        WqpP[p] = pack2(W_qproj[(2 * p) * HDIM + tid],
                        W_qproj[(2 * p + 1) * HDIM + tid]);
    u32 WapP[16];                   // W_attn_proj dims 32q.., output o
    #pragma unroll
    for (int i = 0; i < 16; ++i)
        WapP[i] = pack2(W_attn_proj[(32 * q + 2 * i) * 8 + o],
                        W_attn_proj[(32 * q + 2 * i + 1) * 8 + o]);
    u32 WabP[4];
    #pragma unroll
    for (int p = 0; p < 4; ++p)
        WabP[p] = pack2(W_attn_back[(2 * p) * HDIM + tid],
                        W_attn_back[(2 * p + 1) * HDIM + tid]);
    const float bqp  = b_qproj[tid];
    const float bap  = b_attn_proj[o] + theta_attn[o];
    const float bab  = b_attn_back[tid];
    const float bias = b_proj[g] + theta_gate[g & 7];

    // ---- init: h = 0, stage x_0 into buffer 0 ----
    if (tid < 128) hS[tid] = 0u;
    {
        float x0  = inputs[(size_t)b * DIN + tid];
        float x0n = dppf<DPP_SHL1>(x0);
        if (!(tid & 1)) xS[tid >> 1] = pack2(x0, x0n);
    }
    float cx = 0.f, hx = 0.f;
    __syncthreads();

    for (int t = 0; t < T_STEPS; ++t) {
        const int xb = (t & 1) << 7;
        float xn = 0.f;
        if (t + 1 < T_STEPS)
            xn = inputs[((size_t)(t + 1) * BATCH + b) * DIN + tid];

        // ---- Phase A: wave w dots its 64-dim x+h slice (8 acc chains) ----
        const int sbase = 32 * w + (lw >> 5) * 16;
        const uint4* xp = (const uint4*)&xS[xb + sbase];
        const uint4* hp = (const uint4*)&hS[sbase];
        uint4 x0 = xp[0], x1 = xp[1], x2 = xp[2], x3 = xp[3];
        uint4 v0 = hp[0], v1 = hp[1], v2 = hp[2], v3 = hp[3];
        float a0 = dot2(x0.x, WxP[ 0], 0.f);
        a0 = dot2(x0.y, WxP[ 1], a0);
        a0 = dot2(x0.z, WxP[ 2], a0);
        a0 = dot2(x0.w, WxP[ 3], a0);
        float a1 = dot2(x1.x, WxP[ 4], 0.f);
        a1 = dot2(x1.y, WxP[ 5], a1);
        a1 = dot2(x1.z, WxP[ 6], a1);
        a1 = dot2(x1.w, WxP[ 7], a1);
        float a2 = dot2(x2.x, WxP[ 8], 0.f);
        a2 = dot2(x2.y, WxP[ 9], a2);
        a2 = dot2(x2.z, WxP[10], a2);
        a2 = dot2(x2.w, WxP[11], a2);
        float a3 = dot2(x3.x, WxP[12], 0.f);
        a3 = dot2(x3.y, WxP[13], a3);
        a3 = dot2(x3.z, WxP[14], a3);
        a3 = dot2(x3.w, WxP[15], a3);
        float a4 = dot2(v0.x, WhP[ 0], 0.f);
        a4 = dot2(v0.y, WhP[ 1], a4);
        a4 = dot2(v0.z, WhP[ 2], a4);
        a4 = dot2(v0.w, WhP[ 3], a4);
        float a5 = dot2(v1.x, WhP[ 4], 0.f);
        a5 = dot2(v1.y, WhP[ 5], a5);
        a5 = dot2(v1.z, WhP[ 6], a5);
        a5 = dot2(v1.w, WhP[ 7], a5);
        float a6 = dot2(v2.x, WhP[ 8], 0.f);
        a6 = dot2(v2.y, WhP[ 9], a6);
        a6 = dot2(v2.z, WhP[10], a6);
        a6 = dot2(v2.w, WhP[11], a6);
        float a7 = dot2(v3.x, WhP[12], 0.f);
        a7 = dot2(v3.y, WhP[13], a7);
        a7 = dot2(v3.z, WhP[14], a7);
        a7 = dot2(v3.w, WhP[15], a7);
        float part = ((a0 + a1) + (a2 + a3)) + ((a4 + a5) + (a6 + a7));
        preS[w * 64 + lw] = part;
        lds_barrier();                          // barrier A
        float pre = (((preS[g      ] + preS[ 32 + g]) +
                      (preS[ 64 + g] + preS[ 96 + g])) +
                     ((preS[128 + g] + preS[160 + g]) +
                      (preS[192 + g] + preS[224 + g]))) + bias;
        float cq = __cosf(pre);

        // prefix/butterfly over the 8 qubits — all DPP, valid in all lanes
        float s = cq;
        { float u1 = dppf<DPP_SHR1>(s); if (q >= 1) s *= u1; }
        { float u2 = dppf<DPP_SHR2>(s); if (q >= 2) s *= u2; }
        { float u4 = dppf<DPP_SHR4>(s); if (q >= 4) s *= u4; }
        float v = (q == 0) ? 1.0f : cq;
        v *= dppf<DPP_XOR1>(v);
        v *= dppf<DPP_XOR2>(v);
        v *= dppf<DPP_HMIR>(v);
        float outv = (q == 0) ? v : s;
        float onx  = dppf<DPP_SHL1>(outv);
        u32 ogv = pack2(outv, onx);             // word j (gates 2j,2j+1) @ lane 2j

        // ---- Phase B/C: qp dots via readlane broadcast (no LDS) ----
        float d0 = dot2(rl(ogv,  0), WqpP[0], bqp);
        d0 = dot2(rl(ogv,  2), WqpP[1], d0);
        d0 = dot2(rl(ogv,  4), WqpP[2], d0);
        d0 = dot2(rl(ogv,  6), WqpP[3], d0);
        float d1 = dot2(rl(ogv,  8), WqpP[0], bqp);
        d1 = dot2(rl(ogv, 10), WqpP[1], d1);
        d1 = dot2(rl(ogv, 12), WqpP[2], d1);
        d1 = dot2(rl(ogv, 14), WqpP[3], d1);
        float d2 = dot2(rl(ogv, 16), WqpP[0], bqp);
        d2 = dot2(rl(ogv, 18), WqpP[1], d2);
        d2 = dot2(rl(ogv, 20), WqpP[2], d2);
        d2 = dot2(rl(ogv, 22), WqpP[3], d2);
        float d3 = dot2(rl(ogv, 24), WqpP[0], bqp);
        d3 = dot2(rl(ogv, 26), WqpP[1], d3);
        d3 = dot2(rl(ogv, 28), WqpP[2], d3);
        d3 = dot2(rl(ogv, 30), WqpP[3], d3);
        float fv = fast_sigmoid(d0);
        float iv = fast_sigmoid(d1);
        float gv = fast_tanh(d2);
        float ov = fast_sigmoid(d3);
        cx = fmaf(fv, cx, iv * gv);
        float hm = ov * fast_tanh(cx);
        float hmn = dppf<DPP_SHL1>(hm);
        if (!(tid & 1))
            hmS[(tid >> 5) * 20 + ((tid >> 1) & 15)] = pack2(hm, hmn);
        lds_barrier();                          // barrier C

        // ---- Phase D: attn projection (redundant per wave) ----
        const uint4* mp = (const uint4*)&hmS[q * 20];
        uint4 m0 = mp[0], m1 = mp[1], m2 = mp[2], m3 = mp[3];
        float s0 = dot2(m0.x, WapP[ 0], 0.f);
        s0 = dot2(m0.y, WapP[ 1], s0);
        s0 = dot2(m0.z, WapP[ 2], s0);
        s0 = dot2(m0.w, WapP[ 3], s0);
        float s1 = dot2(m1.x, WapP[ 4], 0.f);
        s1 = dot2(m1.y, WapP[ 5], s1);
        s1 = dot2(m1.z, WapP[ 6], s1);
        s1 = dot2(m1.w, WapP[ 7], s1);
        float s2 = dot2(m2.x, WapP[ 8], 0.f);
        s2 = dot2(m2.y, WapP[ 9], s2);
        s2 = dot2(m2.z, WapP[10], s2);
        s2 = dot2(m2.w, WapP[11], s2);
        float s3 = dot2(m3.x, WapP[12], 0.f);
        s3 = dot2(m3.y, WapP[13], s3);
        s3 = dot2(m3.z, WapP[14], s3);
        s3 = dot2(m3.w, WapP[15], s3);
        float sd = (s0 + s1) + (s2 + s3);
        sd += dppf<DPP_XOR1>(sd);
        sd += dppf<DPP_XOR2>(sd);
        sd += dppf<DPP_HMIR>(sd);
        float co = __cosf(sd + bap);            // output o's cosine @ lanes 8o..

        // ---- Phase E: cosines via readlane (no LDS); hx = oq . Wab + b ----
        float ca0 = rlf(co,  0), ca1 = rlf(co,  8);
        float ca2 = rlf(co, 16), ca3 = rlf(co, 24);
        float ca4 = rlf(co, 32), ca5 = rlf(co, 40);
        float ca6 = rlf(co, 48), ca7 = rlf(co, 56);
        float p1 = ca0 * ca1;
        float p2 = p1 * ca2;
        float p3 = p2 * ca3;
        float p4 = p3 * ca4;
        float p5 = p4 * ca5;
        float p6 = p5 * ca6;
        float p7 = p6 * ca7;
        float q12 = ca1 * ca2, q34 = ca3 * ca4, q56 = ca5 * ca6;
        float p0 = (q12 * q34) * (q56 * ca7);
        u32 oq0 = pack2(p0, p1);
        u32 oq1 = pack2(p2, p3);
        u32 oq2 = pack2(p4, p5);
        u32 oq3 = pack2(p6, p7);
        float hv = dot2(oq0, WabP[0], bab);
        hv = dot2(oq1, WabP[1], hv);
        hv = dot2(oq2, WabP[2], hv);
        hv = dot2(oq3, WabP[3], hv);
        hx = hv;
        out[((size_t)t * BATCH + b) * HDIM + tid] = hx;
        float hxn = dppf<DPP_SHL1>(hx);
        if (!(tid & 1))
            hS[tid >> 1] = pack2(hx, hxn);
        {
            float xnx = dppf<DPP_SHL1>(xn);
            if (!(tid & 1)) xS[(xb ^ 128) + (tid >> 1)] = pack2(xn, xnx);
        }
        // no barrier E: hS/xS intra-wave; preS WAR covered by barrier C,
        // hmS WAR covered by next step's barrier A
    }

    const size_t base = (size_t)T_STEPS * BATCH * HDIM;
    out[base + (size_t)b * HDIM + tid] = hx;
    out[base + (size_t)BATCH * HDIM + (size_t)b * HDIM + tid] = cx;
}

extern "C" void kernel_launch(void* const* d_in, const int* in_sizes, int n_in,
                              void* d_out, int out_size, void* d_ws, size_t ws_size,
                              hipStream_t stream) {
    const float* inputs      = (const float*)d_in[0];
    const float* W_proj      = (const float*)d_in[1];
    const float* b_proj      = (const float*)d_in[2];
    const float* theta_gate  = (const float*)d_in[3];
    const float* W_qproj     = (const float*)d_in[4];
    const float* b_qproj     = (const float*)d_in[5];
    const float* theta_attn  = (const float*)d_in[6];
    const float* W_attn_proj = (const float*)d_in[7];
    const float* b_attn_proj = (const float*)d_in[8];
    const float* W_attn_back = (const float*)d_in[9];
    const float* b_attn_back = (const float*)d_in[10];
    float* outp = (float*)d_out;

    qlstm_fused<<<BATCH, 256, 0, stream>>>(
        inputs, W_proj, b_proj, theta_gate, W_qproj, b_qproj, theta_attn,
        W_attn_proj, b_attn_proj, W_attn_back, b_attn_back, outp);
}

// Round 13
// 279.908 us; speedup vs baseline: 1.3018x; 1.0593x over previous
//
#include <hip/hip_runtime.h>

#define T_STEPS 256
#define BATCH   512
#define DIN     256
#define HDIM    256

typedef unsigned int u32;
typedef _Float16 h2 __attribute__((ext_vector_type(2)));

__device__ __forceinline__ u32 pack2(float a, float b) {
    return __builtin_bit_cast(u32, __builtin_amdgcn_cvt_pkrtz(a, b));
}
__device__ __forceinline__ float dot2(u32 a, u32 b, float acc) {
    return __builtin_amdgcn_fdot2(__builtin_bit_cast(h2, a),
                                  __builtin_bit_cast(h2, b), acc, false);
}
__device__ __forceinline__ float rcpf(float x) { return __builtin_amdgcn_rcpf(x); }
__device__ __forceinline__ float fast_sigmoid(float x) {
    return rcpf(1.0f + __expf(-x));
}
__device__ __forceinline__ float fast_tanh(float x) {
    return 1.0f - 2.0f * rcpf(__expf(2.0f * x) + 1.0f);
}

// DPP lane permute (VALU, not DS pipe). Invalid lanes keep own value.
template<int CTRL>
__device__ __forceinline__ float dppf(float x) {
    int xi = __builtin_bit_cast(int, x);
    return __builtin_bit_cast(float,
        __builtin_amdgcn_update_dpp(xi, xi, CTRL, 0xF, 0xF, false));
}
#define DPP_XOR1  0xB1   // quad_perm [1,0,3,2]
#define DPP_XOR2  0x4E   // quad_perm [2,3,0,1]
#define DPP_HMIR  0x141  // row_half_mirror (xor4 on quad-uniform data)
#define DPP_SHR1  0x111  // lane i <- i-1
#define DPP_SHR2  0x112
#define DPP_SHR4  0x114
#define DPP_SHL1  0x101  // lane i <- i+1

// LDS-only barrier: don't drain vmcnt (global loads/stores stay in flight)
__device__ __forceinline__ void lds_barrier() {
    asm volatile("s_waitcnt lgkmcnt(0)\n\ts_barrier" ::: "memory");
}

// ---------------------------------------------------------------------------
// Fused QLSTM (r10 structure + x-dot hoisted off the critical path).
// 4 waves/batch-element, TWO lgkm-only barriers per step.
// Phase A = h-dot only + precomputed partX. partX(t+1) is computed in the
// post-barrier-C slack (with Phase D/E): stage x_{t+1} (loaded at step top,
// ~1300 cyc earlier) into the single xS buffer, re-read this wave's slice,
// 16 dot2. All xS flows are intra-wave and in-order.
// ---------------------------------------------------------------------------
__launch_bounds__(256, 2)
__global__ void qlstm_fused(const float* __restrict__ inputs,
                            const float* __restrict__ W_proj,
                            const float* __restrict__ b_proj,
                            const float* __restrict__ theta_gate,
                            const float* __restrict__ W_qproj,
                            const float* __restrict__ b_qproj,
                            const float* __restrict__ theta_attn,
                            const float* __restrict__ W_attn_proj,
                            const float* __restrict__ b_attn_proj,
                            const float* __restrict__ W_attn_back,
                            const float* __restrict__ b_attn_back,
                            float* __restrict__ out) {
    const int tid  = threadIdx.x;
    const int b    = blockIdx.x;
    const int w    = tid >> 6;      // wave 0..3
    const int lw   = tid & 63;      // lane in wave
    const int g    = lw & 31;       // gate 0..31 (phase A)
    const int q    = lw & 7;        // hm chunk (D)
    const int o    = lw >> 3;       // attn output (D)

    __shared__ __align__(16) u32 hS[128];     // h    f16[256] packed
    __shared__ __align__(16) u32 xS[128];     // x_t  f16[256] (single buffer)
    __shared__ __align__(16) u32 hmS[160];    // hmid f16[256], stride-20 chunks
    __shared__ __align__(16) u32 ogS[64];     // 4 waves x 16 u32
    __shared__ __align__(16) float caS[32];   // 4 waves x 8 attn cosines
    __shared__ __align__(16) float preS[256]; // 4 waves x 64 half-partials

    // ---- register-resident weights ----
    u32 WxP[16], WhP[16];
    {
        const int dbase = 64 * w + (lw >> 5) * 32;
        #pragma unroll
        for (int i = 0; i < 16; ++i) {
            WxP[i] = pack2(W_proj[(dbase + 2 * i) * 32 + g],
                           W_proj[(dbase + 2 * i + 1) * 32 + g]);
            WhP[i] = pack2(W_proj[(DIN + dbase + 2 * i) * 32 + g],
                           W_proj[(DIN + dbase + 2 * i + 1) * 32 + g]);
        }
    }
    u32 WqpP[4];
    #pragma unroll
    for (int p = 0; p < 4; ++p)
        WqpP[p] = pack2(W_qproj[(2 * p) * HDIM + tid],
                        W_qproj[(2 * p + 1) * HDIM + tid]);
    u32 WapP[16];                   // W_attn_proj dims 32q.., output o
    #pragma unroll
    for (int i = 0; i < 16; ++i)
        WapP[i] = pack2(W_attn_proj[(32 * q + 2 * i) * 8 + o],
                        W_attn_proj[(32 * q + 2 * i + 1) * 8 + o]);
    u32 WabP[4];
    #pragma unroll
    for (int p = 0; p < 4; ++p)
        WabP[p] = pack2(W_attn_back[(2 * p) * HDIM + tid],
                        W_attn_back[(2 * p + 1) * HDIM + tid]);
    const float bqp  = b_qproj[tid];
    const float bap  = b_attn_proj[o] + theta_attn[o];
    const float bab  = b_attn_back[tid];
    const float bias = b_proj[g] + theta_gate[g & 7];

    // ---- init: h = 0, stage x_0, precompute partX for t = 0 ----
    if (tid < 128) hS[tid] = 0u;
    {
        float x0  = inputs[(size_t)b * DIN + tid];
        float x0n = dppf<DPP_SHL1>(x0);
        if (!(tid & 1)) xS[tid >> 1] = pack2(x0, x0n);
    }
    float cx = 0.f, hx = 0.f;
    __syncthreads();

    const int sbase = 32 * w + (lw >> 5) * 16;   // this lane's u32 slice base
    float partX;
    {
        const uint4* xp = (const uint4*)&xS[sbase];
        uint4 x0 = xp[0], x1 = xp[1], x2 = xp[2], x3 = xp[3];
        float a0 = dot2(x0.x, WxP[ 0], 0.f);
        a0 = dot2(x0.y, WxP[ 1], a0);
        a0 = dot2(x0.z, WxP[ 2], a0);
        a0 = dot2(x0.w, WxP[ 3], a0);
        float a1 = dot2(x1.x, WxP[ 4], 0.f);
        a1 = dot2(x1.y, WxP[ 5], a1);
        a1 = dot2(x1.z, WxP[ 6], a1);
        a1 = dot2(x1.w, WxP[ 7], a1);
        float a2 = dot2(x2.x, WxP[ 8], 0.f);
        a2 = dot2(x2.y, WxP[ 9], a2);
        a2 = dot2(x2.z, WxP[10], a2);
        a2 = dot2(x2.w, WxP[11], a2);
        float a3 = dot2(x3.x, WxP[12], 0.f);
        a3 = dot2(x3.y, WxP[13], a3);
        a3 = dot2(x3.z, WxP[14], a3);
        a3 = dot2(x3.w, WxP[15], a3);
        partX = (a0 + a1) + (a2 + a3);
    }

    for (int t = 0; t < T_STEPS; ++t) {
        float xn = 0.f;
        if (t + 1 < T_STEPS)
            xn = inputs[((size_t)(t + 1) * BATCH + b) * DIN + tid];

        // ---- Phase A: h-dot only (x contribution precomputed) ----
        const uint4* hp = (const uint4*)&hS[sbase];
        uint4 v0 = hp[0], v1 = hp[1], v2 = hp[2], v3 = hp[3];
        float a4 = dot2(v0.x, WhP[ 0], 0.f);
        a4 = dot2(v0.y, WhP[ 1], a4);
        a4 = dot2(v0.z, WhP[ 2], a4);
        a4 = dot2(v0.w, WhP[ 3], a4);
        float a5 = dot2(v1.x, WhP[ 4], 0.f);
        a5 = dot2(v1.y, WhP[ 5], a5);
        a5 = dot2(v1.z, WhP[ 6], a5);
        a5 = dot2(v1.w, WhP[ 7], a5);
        float a6 = dot2(v2.x, WhP[ 8], 0.f);
        a6 = dot2(v2.y, WhP[ 9], a6);
        a6 = dot2(v2.z, WhP[10], a6);
        a6 = dot2(v2.w, WhP[11], a6);
        float a7 = dot2(v3.x, WhP[12], 0.f);
        a7 = dot2(v3.y, WhP[13], a7);
        a7 = dot2(v3.z, WhP[14], a7);
        a7 = dot2(v3.w, WhP[15], a7);
        float part = ((a4 + a5) + (a6 + a7)) + partX;
        preS[w * 64 + lw] = part;
        lds_barrier();                          // barrier A
        float pre = (((preS[g      ] + preS[ 32 + g]) +
                      (preS[ 64 + g] + preS[ 96 + g])) +
                     ((preS[128 + g] + preS[160 + g]) +
                      (preS[192 + g] + preS[224 + g]))) + bias;
        float cq = __cosf(pre);

        // prefix/butterfly over the 8 qubits — all DPP
        float s = cq;
        { float u1 = dppf<DPP_SHR1>(s); if (q >= 1) s *= u1; }
        { float u2 = dppf<DPP_SHR2>(s); if (q >= 2) s *= u2; }
        { float u4 = dppf<DPP_SHR4>(s); if (q >= 4) s *= u4; }
        float v = (q == 0) ? 1.0f : cq;
        v *= dppf<DPP_XOR1>(v);
        v *= dppf<DPP_XOR2>(v);
        v *= dppf<DPP_HMIR>(v);
        float outv = (q == 0) ? v : s;
        float onx  = dppf<DPP_SHL1>(outv);
        if (lw < 32 && !(lw & 1))
            ogS[w * 16 + (lw >> 1)] = pack2(outv, onx);
        // intra-wave LDS RAW -> compiler lgkmcnt wait, no barrier

        // ---- Phase B/C: qp dots + activations + LSTM cell (lane = h-dim) ----
        const uint4* ogp = (const uint4*)&ogS[w * 16];
        uint4 og0 = ogp[0], og1 = ogp[1], og2 = ogp[2], og3 = ogp[3];
        float d0 = dot2(og0.x, WqpP[0], bqp);
        d0 = dot2(og0.y, WqpP[1], d0);
        d0 = dot2(og0.z, WqpP[2], d0);
        d0 = dot2(og0.w, WqpP[3], d0);
        float d1 = dot2(og1.x, WqpP[0], bqp);
        d1 = dot2(og1.y, WqpP[1], d1);
        d1 = dot2(og1.z, WqpP[2], d1);
        d1 = dot2(og1.w, WqpP[3], d1);
        float d2 = dot2(og2.x, WqpP[0], bqp);
        d2 = dot2(og2.y, WqpP[1], d2);
        d2 = dot2(og2.z, WqpP[2], d2);
        d2 = dot2(og2.w, WqpP[3], d2);
        float d3 = dot2(og3.x, WqpP[0], bqp);
        d3 = dot2(og3.y, WqpP[1], d3);
        d3 = dot2(og3.z, WqpP[2], d3);
        d3 = dot2(og3.w, WqpP[3], d3);
        float fv = fast_sigmoid(d0);
        float iv = fast_sigmoid(d1);
        float gv = fast_tanh(d2);
        float ov = fast_sigmoid(d3);
        cx = fmaf(fv, cx, iv * gv);
        float hm = ov * fast_tanh(cx);
        float hmn = dppf<DPP_SHL1>(hm);
        if (!(tid & 1))
            hmS[(tid >> 5) * 20 + ((tid >> 1) & 15)] = pack2(hm, hmn);
        lds_barrier();                          // barrier C

        // ---- Phase D: attn projection (redundant per wave) ----
        const uint4* mp = (const uint4*)&hmS[q * 20];
        uint4 m0 = mp[0], m1 = mp[1], m2 = mp[2], m3 = mp[3];
        float s0 = dot2(m0.x, WapP[ 0], 0.f);
        s0 = dot2(m0.y, WapP[ 1], s0);
        s0 = dot2(m0.z, WapP[ 2], s0);
        s0 = dot2(m0.w, WapP[ 3], s0);
        float s1 = dot2(m1.x, WapP[ 4], 0.f);
        s1 = dot2(m1.y, WapP[ 5], s1);
        s1 = dot2(m1.z, WapP[ 6], s1);
        s1 = dot2(m1.w, WapP[ 7], s1);
        float s2 = dot2(m2.x, WapP[ 8], 0.f);
        s2 = dot2(m2.y, WapP[ 9], s2);
        s2 = dot2(m2.z, WapP[10], s2);
        s2 = dot2(m2.w, WapP[11], s2);
        float s3 = dot2(m3.x, WapP[12], 0.f);
        s3 = dot2(m3.y, WapP[13], s3);
        s3 = dot2(m3.z, WapP[14], s3);
        s3 = dot2(m3.w, WapP[15], s3);
        float sd = (s0 + s1) + (s2 + s3);
        sd += dppf<DPP_XOR1>(sd);
        sd += dppf<DPP_XOR2>(sd);
        sd += dppf<DPP_HMIR>(sd);
        float co = __cosf(sd + bap);
        if (!(lw & 7)) caS[w * 8 + o] = co;     // per-wave copy, same-wave read

        // ---- stage x_{t+1} + compute partX for t+1 (off critical path) ----
        {
            float xnx = dppf<DPP_SHL1>(xn);
            if (!(tid & 1)) xS[tid >> 1] = pack2(xn, xnx);
            const uint4* xp2 = (const uint4*)&xS[sbase];
            uint4 y0 = xp2[0], y1 = xp2[1], y2 = xp2[2], y3 = xp2[3];
            float b0 = dot2(y0.x, WxP[ 0], 0.f);
            b0 = dot2(y0.y, WxP[ 1], b0);
            b0 = dot2(y0.z, WxP[ 2], b0);
            b0 = dot2(y0.w, WxP[ 3], b0);
            float b1 = dot2(y1.x, WxP[ 4], 0.f);
            b1 = dot2(y1.y, WxP[ 5], b1);
            b1 = dot2(y1.z, WxP[ 6], b1);
            b1 = dot2(y1.w, WxP[ 7], b1);
            float b2 = dot2(y2.x, WxP[ 8], 0.f);
            b2 = dot2(y2.y, WxP[ 9], b2);
            b2 = dot2(y2.z, WxP[10], b2);
            b2 = dot2(y2.w, WxP[11], b2);
            float b3 = dot2(y3.x, WxP[12], 0.f);
            b3 = dot2(y3.y, WxP[13], b3);
            b3 = dot2(y3.z, WxP[14], b3);
            b3 = dot2(y3.w, WxP[15], b3);
            partX = (b0 + b1) + (b2 + b3);
        }

        // ---- Phase E: hx = attn-qgate . W_attn_back + b (lane = h-dim) ----
        float4 cA = *(const float4*)&caS[w * 8];
        float4 cB = *(const float4*)&caS[w * 8 + 4];
        float p1 = cA.x * cA.y;
        float p2 = p1 * cA.z;
        float p3 = p2 * cA.w;
        float p4 = p3 * cB.x;
        float p5 = p4 * cB.y;
        float p6 = p5 * cB.z;
        float p7 = p6 * cB.w;
        float q12 = cA.y * cA.z, q34 = cA.w * cB.x, q56 = cB.y * cB.z;
        float p0 = (q12 * q34) * (q56 * cB.w);
        u32 oq0 = pack2(p0, p1);
        u32 oq1 = pack2(p2, p3);
        u32 oq2 = pack2(p4, p5);
        u32 oq3 = pack2(p6, p7);
        float hv = dot2(oq0, WabP[0], bab);
        hv = dot2(oq1, WabP[1], hv);
        hv = dot2(oq2, WabP[2], hv);
        hv = dot2(oq3, WabP[3], hv);
        hx = hv;
        out[((size_t)t * BATCH + b) * HDIM + tid] = hx;
        float hxn = dppf<DPP_SHL1>(hx);
        if (!(tid & 1))
            hS[tid >> 1] = pack2(hx, hxn);
        // no barrier E: hS/xS intra-wave; preS WAR covered by barrier C,
        // hmS WAR covered by next step's barrier A
    }

    const size_t base = (size_t)T_STEPS * BATCH * HDIM;
    out[base + (size_t)b * HDIM + tid] = hx;
    out[base + (size_t)BATCH * HDIM + (size_t)b * HDIM + tid] = cx;
}

extern "C" void kernel_launch(void* const* d_in, const int* in_sizes, int n_in,
                              void* d_out, int out_size, void* d_ws, size_t ws_size,
                              hipStream_t stream) {
    const float* inputs      = (const float*)d_in[0];
    const float* W_proj      = (const float*)d_in[1];
    const float* b_proj      = (const float*)d_in[2];
    const float* theta_gate  = (const float*)d_in[3];
    const float* W_qproj     = (const float*)d_in[4];
    const float* b_qproj     = (const float*)d_in[5];
    const float* theta_attn  = (const float*)d_in[6];
    const float* W_attn_proj = (const float*)d_in[7];
    const float* b_attn_proj = (const float*)d_in[8];
    const float* W_attn_back = (const float*)d_in[9];
    const float* b_attn_back = (const float*)d_in[10];
    float* outp = (float*)d_out;

    qlstm_fused<<<BATCH, 256, 0, stream>>>(
        inputs, W_proj, b_proj, theta_gate, W_qproj, b_qproj, theta_attn,
        W_attn_proj, b_attn_proj, W_attn_back, b_attn_back, outp);
}